// Round 1
// baseline (500.522 us; speedup 1.0000x reference)
//
#include <hip/hip_runtime.h>
#include <stdint.h>

// PyramidAttention gfx950 — round 14: wave-specialized producer/consumer k_attn.
// Waves 0-3 (S-waves) compute S=A·B + softmax P, each owning 2 row-blocks so
// every B fragment is read by 2 waves instead of 4 (72->36KB/chunk). Waves 4-7
// (Z-waves) run the Z-GEMM one chunk behind, each owning a distinct 144-col
// range with all 4 P row-blocks in regs, so every R fragment is read once
// (72->36KB/chunk, reused across 4 MFMAs). S-state (af, 72 regs) and Z-state
// (acc, 144 regs) alias one f32x4 st[36] array (roles are disjoint) to keep
// the register frame ~196 < 256. Rl drops to double-buffer (LDS 152->116KB).
// Chunk LDS traffic 223->147KB; MFMA pipe per SIMD unchanged (1 S + 1 Z wave).
// Everything else (packing formats, swizzles, DMA cadence, grid mapping,
// prep/epilogue kernels, workspace layout) identical to R13.

typedef __attribute__((ext_vector_type(8))) short bf16x8;
typedef __attribute__((ext_vector_type(4))) float f32x4;
typedef unsigned short ushort_t;

#define L_TOT  13326
#define NCHT   417
#define NPIX   4096
#define BCHUNK_E 9216  // 32 cols * 288 k
#define RCHUNK_E 18432 // 576 cols * 32 l
#define LOG2E10 14.4269504f   // 10*log2(e)
#define CT 256         // k_convref l-tile

__device__ __forceinline__ float cubw(float d) {
  d = fabsf(d);
  if (d <= 1.f) return (1.25f * d - 2.25f) * d * d + 1.f;          // A=-0.75
  if (d < 2.f)  return ((-0.75f * d + 3.75f) * d - 6.f) * d + 3.f;
  return 0.f;
}

__device__ __forceinline__ void decode_l(int l, int& S, int& off) {
  if (l < 4096)       { S = 64; off = 0; }
  else if (l < 7345)  { S = 57; off = 4096; }
  else if (l < 9946)  { S = 51; off = 7345; }
  else if (l < 11882) { S = 44; off = 9946; }
  else                { S = 38; off = 11882; }
}

__device__ __forceinline__ ushort_t f2bf(float f) {
  union { float f; uint32_t u; } v; v.f = f;
  uint32_t r = (v.u + 0x7fffu + ((v.u >> 16) & 1u)) >> 16;  // RNE
  return (ushort_t)r;
}

__device__ __forceinline__ float preluf(float x, float a) { return x >= 0.f ? x : a * x; }

__device__ __forceinline__ void gll16(const ushort_t* g, ushort_t* l) {
  __builtin_amdgcn_global_load_lds(
      (const __attribute__((address_space(1))) unsigned int*)g,
      (__attribute__((address_space(3))) unsigned int*)l, 16, 0, 0);
}

// ---------------- K2: bicubic + conv1x1 + prelu fused ----------------
__global__ void k_convref(const float* __restrict__ inref,
                          const float* __restrict__ Wm, const float* __restrict__ bm,
                          const float* __restrict__ Wa, const float* __restrict__ ba,
                          const float* __restrict__ ap,
                          float* __restrict__ mref, float* __restrict__ aref) {
  __shared__ float T[64][CT];
  __shared__ float Wy[CT][5], Wx[CT][5];
  __shared__ int   IY[CT], IX[CT];
  int blk = blockIdx.x;
  int oh = blk & 1; int lt = (blk >> 1) % 53; int b = blk / 106;
  int l0 = lt * CT;
  int tid = threadIdx.x;
  float a = ap[0];
  {
    int gl = l0 + tid;
    if (gl < L_TOT) {
      int S, off; decode_l(gl, S, off);
      int li = gl - off; int ly = li / S, lx = li % S;
      if (S == 64) {
        IY[tid] = -1; IX[tid] = ly * 64 + lx;
      } else {
        float sc = (float)(63.0 / (double)(S - 1));
        float sy = (float)ly * sc, sx = (float)lx * sc;
        int iy = (int)floorf(sy), ix = (int)floorf(sx);
        float fy = sy - (float)iy, fx = sx - (float)ix;
        IY[tid] = iy; IX[tid] = ix;
        Wy[tid][0] = cubw(fy + 1.f); Wy[tid][1] = cubw(fy);
        Wy[tid][2] = cubw(1.f - fy); Wy[tid][3] = cubw(2.f - fy);
        Wx[tid][0] = cubw(fx + 1.f); Wx[tid][1] = cubw(fx);
        Wx[tid][2] = cubw(1.f - fx); Wx[tid][3] = cubw(2.f - fx);
      }
    }
  }
  __syncthreads();
  for (int i = tid; i < 64 * CT; i += 256) {
    int c = i >> 8; int l2 = i & 255;
    int gl = l0 + l2;
    float val = 0.f;
    if (gl < L_TOT) {
      const float* img = inref + (size_t)(b * 64 + c) * 4096;
      int iy = IY[l2];
      if (iy == -1) {
        val = img[IX[l2]];
      } else {
        int ix = IX[l2];
        #pragma unroll
        for (int t = 0; t < 4; ++t) {
          int ty = iy - 1 + t; ty = ty < 0 ? 0 : (ty > 63 ? 63 : ty);
          float rv = 0.f;
          #pragma unroll
          for (int u = 0; u < 4; ++u) {
            int tx = ix - 1 + u; tx = tx < 0 ? 0 : (tx > 63 ? 63 : tx);
            rv += Wx[l2][u] * img[ty * 64 + tx];
          }
          val += Wy[l2][t] * rv;
        }
      }
    }
    T[c][l2] = val;
  }
  __syncthreads();
  int gl = l0 + tid;
  if (gl >= L_TOT) return;
  for (int oc = oh * 48; oc < oh * 48 + 48; ++oc) {
    const float* Wrow; float s;
    if (oc < 32) { Wrow = Wm + oc * 64; s = bm[oc]; }
    else         { Wrow = Wa + (oc - 32) * 64; s = ba[oc - 32]; }
    #pragma unroll 8
    for (int c = 0; c < 64; ++c) s += Wrow[c] * T[c][tid];
    s = preluf(s, a);
    if (oc < 32) mref[(size_t)(b * 32 + oc) * L_TOT + gl] = s;
    else         aref[(size_t)(b * 64 + oc - 32) * L_TOT + gl] = s;
  }
}

// ---------------- K3: match_base = prelu(Wb@input+bb) ----------------
__global__ void k_mb(const float* __restrict__ input, const float* __restrict__ Wb,
                     const float* __restrict__ bb, const float* __restrict__ ap,
                     float* __restrict__ mbb, int n) {
  int idx = blockIdx.x * 256 + threadIdx.x;
  if (idx >= n) return;                      // n = 2*32*NPIX
  int p = idx % NPIX; int cm = (idx / NPIX) % 32; int b = idx / (32 * NPIX);
  float a = ap[0];
  float acc = bb[cm];
  for (int c = 0; c < 64; ++c) acc += Wb[cm * 64 + c] * input[(size_t)(b * 64 + c) * NPIX + p];
  mbb[(size_t)(b * 32 + cm) * NPIX + p] = preluf(acc, a);
}

// ---------------- K4s1: ssq U ssqA ----------------
__global__ void k_stage1(const float* __restrict__ mref, const float* __restrict__ mbb,
                         float* __restrict__ ssq, float* __restrict__ ssqA, int n) {
  int idx = blockIdx.x * 256 + threadIdx.x;
  if (idx >= n) return;                      // n = 2*L_TOT + 2*NPIX
  if (idx < 2 * L_TOT) {
    int l = idx % L_TOT; int b = idx / L_TOT;
    float s = 0.f;
    for (int c = 0; c < 32; ++c) { float v = mref[(size_t)(b * 32 + c) * L_TOT + l]; s += v * v; }
    ssq[idx] = s;
  } else {
    int j = idx - 2 * L_TOT;
    int p = j % NPIX; int b = j / NPIX;
    float s = 0.f;
    for (int c = 0; c < 32; ++c) { float v = mbb[(size_t)(b * 32 + c) * NPIX + p]; s += v * v; }
    ssqA[j] = s;
  }
}

// ---------------- K4s2: invn U Mlog ----------------
__global__ void k_stage2(const float* __restrict__ ssq, const float* __restrict__ ssqA,
                         float* __restrict__ invn, float* __restrict__ Mlog, int n) {
  int idx = blockIdx.x * 256 + threadIdx.x;
  if (idx >= n) return;                      // n = 2*L_TOT + 2*NPIX
  if (idx < 2 * L_TOT) {
    int l = idx % L_TOT; int b = idx / L_TOT;
    int S, off; decode_l(l, S, off);
    int li = l - off; int ly = li / S, lx = li % S;
    float acc = 0.f;
    for (int dy = -1; dy <= 1; ++dy) {
      int ny = ly + dy; if (ny < 0 || ny >= S) continue;
      for (int dx = -1; dx <= 1; ++dx) {
        int nx = lx + dx; if (nx < 0 || nx >= S) continue;
        acc += ssq[(size_t)b * L_TOT + off + ny * S + nx];
      }
    }
    float nrm = sqrtf(acc); nrm = fmaxf(nrm, 1e-4f);
    invn[idx] = 1.f / nrm;
  } else {
    int j = idx - 2 * L_TOT;
    int p = j % NPIX; int b = j / NPIX;
    int y = p / 64, x = p % 64;
    float acc = 0.f;
    for (int dy = -1; dy <= 1; ++dy) {
      int ny = y + dy; if (ny < 0 || ny >= 64) continue;
      for (int dx = -1; dx <= 1; ++dx) {
        int nx = x + dx; if (nx < 0 || nx >= 64) continue;
        acc += ssqA[(size_t)b * NPIX + ny * 64 + nx];
      }
    }
    float qn = sqrtf(acc);
    float m = fmaxf(0.7f * qn, qn - 7.f);
    Mlog[j] = LOG2E10 * m;
  }
}

// ---------------- K5/6/7 merged: Bs U Am U Rs packing, vec8 ----------------
#define N_BS (2 * NCHT * 1152)
#define N_AIM (2 * NPIX * 36)
#define N_RS (2 * NCHT * 576 * 4)
__global__ void k_pack(const float* __restrict__ mref, const float* __restrict__ invn,
                       const float* __restrict__ mbb, const float* __restrict__ aref,
                       ushort_t* __restrict__ Bs, ushort_t* __restrict__ Am,
                       ushort_t* __restrict__ Rs, int n) {
  int idx = blockIdx.x * 256 + threadIdx.x;
  if (idx >= n) return;
  ushort_t v[8];
  if (idx < N_BS) {
    int segp = idx % 36; int col = (idx / 36) % 32;
    int ch = (idx / 1152) % NCHT; int b = idx / (1152 * NCHT);
    int segl = (segp & ~3) | ((segp & 3) ^ ((col >> 1) & 3));
    int l = ch * 32 + col;
    if (l < L_TOT) {
      int S, off; decode_l(l, S, off);
      int li = l - off; int ly = li / S, lx = li % S;
      float iv = invn[(size_t)b * L_TOT + l];
      #pragma unroll
      for (int e = 0; e < 8; ++e) {
        int k = segl * 8 + e;
        int c = k / 9; int r = k % 9; int dy = r / 3 - 1, dx = r % 3 - 1;
        int ny = ly + dy, nx = lx + dx;
        float val = 0.f;
        if (ny >= 0 && ny < S && nx >= 0 && nx < S)
          val = mref[(size_t)(b * 32 + c) * L_TOT + off + ny * S + nx] * iv;
        v[e] = f2bf(val);
      }
    } else {
      #pragma unroll
      for (int e = 0; e < 8; ++e) v[e] = 0;
    }
    *(uint4*)(Bs + ((size_t)(b * NCHT + ch) * BCHUNK_E + col * 288 + segp * 8)) = *(const uint4*)v;
  } else if (idx < N_BS + N_AIM) {
    int j = idx - N_BS;
    int k8 = j % 36; int p = (j / 36) % NPIX; int b = j / (36 * NPIX);
    int y = p / 64, x = p % 64;
    #pragma unroll
    for (int e = 0; e < 8; ++e) {
      int k = k8 * 8 + e;
      int c = k / 9; int r = k % 9; int dy = r / 3 - 1, dx = r % 3 - 1;
      int ny = y + dy, nx = x + dx;
      float val = 0.f;
      if (ny >= 0 && ny < 64 && nx >= 0 && nx < 64)
        val = mbb[(size_t)(b * 32 + c) * NPIX + ny * 64 + nx];
      v[e] = f2bf(val);
    }
    *(uint4*)(Am + ((size_t)(b * NPIX + p) * 288 + k8 * 8)) = *(const uint4*)v;
  } else {
    int j = idx - N_BS - N_AIM;
    int phys = j & 3; int q = j >> 2;
    int col = q % 576; q /= 576;
    int ch = q % NCHT; int b = q / NCHT;
    int c = col / 9; int r = col % 9; int dy = r / 3 - 1, dx = r % 3 - 1;
    int seg = phys ^ ((col >> 1) & 3);
    int lbase = ch * 32 + seg * 8;
    #pragma unroll
    for (int e = 0; e < 8; ++e) {
      int l = lbase + e;
      float val = 0.f;
      if (l < L_TOT) {
        int S, off; decode_l(l, S, off);
        int li = l - off; int ly = li / S, lx = li % S;
        int ny = ly + dy, nx = lx + dx;
        if (ny >= 0 && ny < S && nx >= 0 && nx < S)
          val = aref[(size_t)(b * 64 + c) * L_TOT + off + ny * S + nx];
      }
      v[e] = f2bf(val);
    }
    *(uint4*)(Rs + ((size_t)(b * NCHT + ch) * RCHUNK_E + col * 32 + phys * 8)) = *(const uint4*)v;
  }
}

// ---------------- K8: M=64 flash attention, wave-specialized S/Z ----------------
// grid 256, XCD swizzle unchanged. Waves 0-3: S(ch)+P(ch). Waves 4-7: Z(ch-1).
// Loop: { S(ch) || Z(ch-1); barrier; DMA B[ch+2],R[ch+1] } -> full-iter cover.
// st[36] f32x4 is the role-union register block: S uses st[0..17] as af[2][9]
// (bf16x8 via bit_cast), Z uses st[0..35] as acc[4][9].
__global__ __launch_bounds__(512, 2) void k_attn(const ushort_t* __restrict__ Am,
                                                 const ushort_t* __restrict__ Bs,
                                                 const ushort_t* __restrict__ Rs,
                                                 const float* __restrict__ Mlog,
                                                 float* __restrict__ Og,
                                                 float* __restrict__ Ol) {
  __shared__ ushort_t Rl[2][RCHUNK_E];   // 73728 B: dbuf R chunk
  __shared__ ushort_t Bl[2][BCHUNK_E];   // 36864 B: dbuf B chunk (swizzled image)
  __shared__ ushort_t Pl[2][2048];       // 8192 B: dbuf P tile 64x32 (swizzled)
  int tid = threadIdx.x;
  int xcd = blockIdx.x & 7; int slot = blockIdx.x >> 3;
  int group = xcd >> 1;
  int spl = group & 1; int b = group >> 1;
  int tile = slot * 2 + (xcd & 1);
  int p0 = tile * 64;
  int wave = tid >> 6, lane = tid & 63, quad = lane >> 4, ln = lane & 15;
  bool isS = wave < 4;                    // round-robin wave->SIMD: 1 S + 1 Z per SIMD
  int rbp = wave & 1, cbh = (wave >> 1) & 1;   // S role: row-blocks {rbp, rbp+2}, col-half
  int g = wave & 3;                       // Z role: cols [g*144, g*144+144)
  int c0 = spl ? 209 : 0, c1 = spl ? NCHT : 209;

  f32x4 st[36];                          // role-union: af (S, 0..17) / acc (Z, 0..35)
  float mlg[2][4], psum[2][4];

  if (isS) {
    #pragma unroll
    for (int h = 0; h < 2; ++h) {
      const ushort_t* arow = Am + (size_t)(b * NPIX + p0 + (rbp + 2 * h) * 16 + ln) * 288;
      #pragma unroll
      for (int kk = 0; kk < 9; ++kk)
        st[h * 9 + kk] = __builtin_bit_cast(f32x4, *(const bf16x8*)(arow + kk * 32 + quad * 8));
      #pragma unroll
      for (int r = 0; r < 4; ++r) {
        mlg[h][r] = Mlog[(size_t)b * NPIX + p0 + (rbp + 2 * h) * 16 + quad * 4 + r];
        psum[h][r] = 0.f;
      }
    }
  } else {
    #pragma unroll
    for (int i = 0; i < 36; ++i) { st[i][0] = 0.f; st[i][1] = 0.f; st[i][2] = 0.f; st[i][3] = 0.f; }
  }

  const ushort_t* RsB = Rs + (size_t)b * NCHT * RCHUNK_E + lane * 8;
  const ushort_t* BsB = Bs + (size_t)b * NCHT * BCHUNK_E + lane * 8;

  auto stageB = [&](int chunk, int sl) {
    const ushort_t* s = BsB + (size_t)chunk * BCHUNK_E;
    ushort_t* d = Bl[sl];
    #pragma unroll
    for (int u = wave; u < 18; u += 8) gll16(s + u * 512, d + u * 512);
  };
  auto stageR = [&](int chunk, int sl) {
    const ushort_t* s = RsB + (size_t)chunk * RCHUNK_E;
    ushort_t* d = Rl[sl];
    #pragma unroll
    for (int u = wave; u < 36; u += 8) gll16(s + u * 512, d + u * 512);
  };

  int col32 = cbh * 16 + ln;
  int bswz = (col32 >> 1) & 3;
  int psw = quad ^ ((ln >> 1) & 3);      // pf read swizzle (Z) — constant per lane

  auto zstep = [&](int parz) {           // Z-GEMM for chunk with parity parz
    bf16x8 pf[4];
    #pragma unroll
    for (int j = 0; j < 4; ++j)
      pf[j] = *(const bf16x8*)&Pl[parz][(j * 16 + ln) * 32 + psw * 8];
    #pragma unroll
    for (int t = 0; t < 9; ++t) {
      int col = g * 144 + t * 16 + ln;
      int swz = quad ^ ((col >> 1) & 3);
      bf16x8 rf = *(const bf16x8*)&Rl[parz][col * 32 + swz * 8];
      #pragma unroll
      for (int j = 0; j < 4; ++j)
        st[j * 9 + t] = __builtin_amdgcn_mfma_f32_16x16x32_bf16(pf[j], rf, st[j * 9 + t], 0, 0, 0);
    }
  };

  // prologue: stage B[c0], B[c0+1], R[c0]; fence before first use
  stageB(c0, c0 & 1);
  stageB(c0 + 1, (c0 + 1) & 1);
  stageR(c0, c0 & 1);
  __syncthreads();

  for (int ch = c0; ch < c1; ++ch) {
    int par = ch & 1;
    if (isS) {
      // S-MFMA from Bl[par]; 2 row-blocks per wave share each B fragment
      f32x4 s0, s1;
      s0[0] = s0[1] = s0[2] = s0[3] = 0.f;
      s1[0] = s1[1] = s1[2] = s1[3] = 0.f;
      #pragma unroll
      for (int kk = 0; kk < 9; ++kk) {
        int segp = kk * 4 + (quad ^ bswz);
        bf16x8 bfrag = *(const bf16x8*)&Bl[par][col32 * 288 + segp * 8];
        s0 = __builtin_amdgcn_mfma_f32_16x16x32_bf16(__builtin_bit_cast(bf16x8, st[kk]), bfrag, s0, 0, 0, 0);
        s1 = __builtin_amdgcn_mfma_f32_16x16x32_bf16(__builtin_bit_cast(bf16x8, st[9 + kk]), bfrag, s1, 0, 0, 0);
      }
      // P = 2^(14.43*s - Mlog); write swizzled dbuf P; deferred row-sum
      int colw = ch * 32 + col32;
      bool valid = colw < L_TOT;
      #pragma unroll
      for (int h = 0; h < 2; ++h)
        #pragma unroll
        for (int r = 0; r < 4; ++r) {
          float sv = h ? s1[r] : s0[r];
          float pv = valid ? exp2f(fmaf(sv, LOG2E10, -mlg[h][r])) : 0.f;
          int row = (rbp + 2 * h) * 16 + quad * 4 + r;
          int seg = cbh * 2 + (ln >> 3);
          int swz = seg ^ ((row >> 1) & 3);
          Pl[par][row * 32 + swz * 8 + (ln & 7)] = f2bf(pv);
          psum[h][r] += pv;
        }
    } else if (ch > c0) {
      zstep(par ^ 1);                    // Z for chunk ch-1
    }
    __syncthreads();   // barrier(ch): drains DMAs issued in iteration ch-1
    // issue DMA with full-iteration cover: B[ch+2] -> Bl[par] (S(ch) done),
    // R[ch+1] -> Rl[par^1] (Z(ch-1) readers done pre-barrier).
    if (ch + 2 < c1) stageB(ch + 2, par);
    if (ch + 1 < c1) stageR(ch + 1, par ^ 1);
  }

  if (isS) {
    // reduce deferred row-sums over the 16 lanes of each quad
    #pragma unroll
    for (int m = 1; m <= 8; m <<= 1)
      #pragma unroll
      for (int h = 0; h < 2; ++h)
        #pragma unroll
        for (int r = 0; r < 4; ++r) psum[h][r] += __shfl_xor(psum[h][r], m);
    int sb2 = spl * 2 + b;
    if (ln == 0) {
      #pragma unroll
      for (int h = 0; h < 2; ++h)
        #pragma unroll
        for (int r = 0; r < 4; ++r) {
          int row = p0 + (rbp + 2 * h) * 16 + quad * 4 + r;
          Ol[(size_t)(sb2 * 2 + cbh) * NPIX + row] = psum[h][r];
        }
    }
  } else {
    zstep((c1 - 1) & 1);                 // final Z chunk (P/R ready; last barrier synced)
    int sb2 = spl * 2 + b;
    #pragma unroll
    for (int j = 0; j < 4; ++j)
      #pragma unroll
      for (int t = 0; t < 9; ++t) {
        int colg = g * 144 + t * 16 + ln;
        #pragma unroll
        for (int r = 0; r < 4; ++r) {
          int row = p0 + j * 16 + quad * 4 + r;
          Og[((size_t)sb2 * NPIX + row) * 576 + colg] = st[j * 9 + t][r];
        }
      }
  }
}

// ---------------- K9: inv = 1 / sum of 4 partial row-sums ----------------
__global__ void k_inv(const float* __restrict__ Ol, float* __restrict__ inv, int n) {
  int idx = blockIdx.x * 256 + threadIdx.x;
  if (idx >= n) return;                      // n = 2*NPIX
  int b = idx / NPIX; int p = idx % NPIX;
  float s = 0.f;
  #pragma unroll
  for (int spl = 0; spl < 2; ++spl)
    #pragma unroll
    for (int cbh = 0; cbh < 2; ++cbh)
      s += Ol[(size_t)(((spl * 2 + b) * 2) + cbh) * NPIX + p];
  inv[idx] = 1.f / s;
}

// ---------------- K10: 9-tap gather, c-fastest lanes + LDS transpose ----------------
__global__ void k_final(const float* __restrict__ Og, const float* __restrict__ inv,
                        const float* __restrict__ input, float* __restrict__ out) {
  __shared__ float T[32][65];
  int blk = blockIdx.x;
  int xh = blk & 1; int y = (blk >> 1) & 63; int b = blk >> 7;
  int tid = threadIdx.x;
  const size_t S1 = (size_t)2 * NPIX * 576;
  for (int it = 0; it < 8; ++it) {
    int lin = it * 256 + tid;
    int c = lin & 63, x32 = lin >> 6;
    int x = xh * 32 + x32;
    float acc = 0.f;
    for (int j = 0; j < 3; ++j) {
      int qy = y + 1 - j; if (qy < 0 || qy >= 64) continue;
      for (int i2 = 0; i2 < 3; ++i2) {
        int qx = x + 1 - i2; if (qx < 0 || qx >= 64) continue;
        int p = qy * 64 + qx;
        size_t e = ((size_t)b * NPIX + p) * 576 + c * 9 + j * 3 + i2;
        acc += (Og[e] + Og[e + S1]) * inv[b * NPIX + p];
      }
    }
    T[x32][c] = acc;
  }
  __syncthreads();
  for (int it = 0; it < 8; ++it) {
    int lin = it * 256 + tid;
    int x32 = lin & 31, c = lin >> 5;
    int o = ((b * 64 + c) * 64 + y) * 64 + xh * 32 + x32;
    out[o] = 0.25f * T[x32][c] + input[o];
  }
}

extern "C" void kernel_launch(void* const* d_in, const int* in_sizes, int n_in,
                              void* d_out, int out_size, void* d_ws, size_t ws_size,
                              hipStream_t stream) {
  (void)in_sizes; (void)n_in; (void)out_size; (void)ws_size;
  const float* input = (const float*)d_in[0];
  const float* inref = (const float*)d_in[1];
  const float* Wb = (const float*)d_in[2];
  const float* bb = (const float*)d_in[3];
  const float* Wm = (const float*)d_in[4];
  const float* bm = (const float*)d_in[5];
  const float* Wa = (const float*)d_in[6];
  const float* ba = (const float*)d_in[7];
  const float* ap = (const float*)d_in[8];
  float* out = (float*)d_out;

  char* ws = (char*)d_ws;
  size_t off = 0;
  auto alloc = [&](size_t bytes) -> char* {
    char* p = ws + off; off = (off + bytes + 255) & ~(size_t)255; return p;
  };
  // persistent region
  ushort_t* Am   = (ushort_t*)alloc((size_t)2 * NPIX * 288 * 2);        // 4.7 MB
  ushort_t* Bs   = (ushort_t*)alloc((size_t)2 * NCHT * BCHUNK_E * 2);   // 15.4 MB
  ushort_t* Rs   = (ushort_t*)alloc((size_t)2 * NCHT * RCHUNK_E * 2);   // 30.7 MB
  float*    Ol   = (float*)alloc((size_t)8 * NPIX * 4);
  float*    inv  = (float*)alloc((size_t)2 * NPIX * 4);
  float*    Mlog = (float*)alloc((size_t)2 * NPIX * 4);
  float*    ssqA = (float*)alloc((size_t)2 * NPIX * 4);
  // big region: Og (37.7 MB) aliases the early prep buffers
  size_t og_bytes = (size_t)4 * NPIX * 576 * 4;
  char* big = alloc(og_bytes);
  float* Og = (float*)big;
  size_t eoff = 0;
  auto ealloc = [&](size_t bytes) -> char* {
    char* p = big + eoff; eoff = (eoff + bytes + 255) & ~(size_t)255; return p;
  };
  float* mref = (float*)ealloc((size_t)2 * 32 * L_TOT * 4);
  float* aref = (float*)ealloc((size_t)2 * 64 * L_TOT * 4);
  float* mbb  = (float*)ealloc((size_t)2 * 32 * NPIX * 4);
  float* ssq  = (float*)ealloc((size_t)2 * L_TOT * 4);
  float* invn = (float*)ealloc((size_t)2 * L_TOT * 4);

  k_convref<<<212, 256, 0, stream>>>(inref, Wm, bm, Wa, ba, ap, mref, aref);
  int n3 = 2 * 32 * NPIX;
  k_mb<<<(n3 + 255) / 256, 256, 0, stream>>>(input, Wb, bb, ap, mbb, n3);
  int ns = 2 * L_TOT + 2 * NPIX;
  k_stage1<<<(ns + 255) / 256, 256, 0, stream>>>(mref, mbb, ssq, ssqA, ns);
  k_stage2<<<(ns + 255) / 256, 256, 0, stream>>>(ssq, ssqA, invn, Mlog, ns);
  int np = N_BS + N_AIM + N_RS;
  k_pack<<<(np + 255) / 256, 256, 0, stream>>>(mref, invn, mbb, aref, Bs, Am, Rs, np);

  k_attn<<<256, 512, 0, stream>>>(Am, Bs, Rs, Mlog, Og, Ol);
  k_inv<<<(2 * NPIX + 255) / 256, 256, 0, stream>>>(Ol, inv, 2 * NPIX);
  k_final<<<256, 256, 0, stream>>>(Og, inv, input, out);
}